// Round 1
// baseline (1059.816 us; speedup 1.0000x reference)
//
#include <hip/hip_runtime.h>

typedef short short8 __attribute__((ext_vector_type(8)));
typedef float f32x4 __attribute__((ext_vector_type(4)));

constexpr int Hdim = 128;   // H
constexpr int Steps = 27;   // COL + ROW - 1
constexpr int Kdim = 384;   // 3H
constexpr int Ndim = 768;   // 6H
constexpr int GSTR = 777;   // g LDS row stride (floats) - bank-conflict-free
constexpr int HSTR = 132;   // h state row stride (floats)

__device__ __forceinline__ short f2bf(float f) {
  unsigned u = __float_as_uint(f);
  u += 0x7FFFu + ((u >> 16) & 1u);          // round-to-nearest-even
  return (short)(u >> 16);
}
__device__ __forceinline__ float bf2f(short s) {
  return __uint_as_float(((unsigned)(unsigned short)s) << 16);
}
__device__ __forceinline__ float sigmoidf_(float x) { return 1.0f / (1.0f + __expf(-x)); }
__device__ __forceinline__ float tanh_(float x) { return 1.0f - 2.0f / (__expf(2.0f * x) + 1.0f); }

// ---- kernel 1: rearrange W_enc (fp32) into MFMA B-fragment-ordered bf16 ----
// layout: idx = ((cls*48 + nt)*12 + ks)*512 + lane*8 + j
// holds W[n = nt*16 + (lane&15)][k = ks*32 + (lane>>4)*8 + j]
__global__ void prep_w(const float* __restrict__ W_enc, short* __restrict__ wfrag) {
  int idx = blockIdx.x * 256 + threadIdx.x;
  if (idx >= 2 * 48 * 12 * 512) return;
  int j = idx & 7;
  int lane = (idx >> 3) & 63;
  int rest = idx >> 9;
  int ks = rest % 12;
  int tmp = rest / 12;
  int nt = tmp % 48;
  int cls = tmp / 48;
  int n = nt * 16 + (lane & 15);
  int k = ks * 32 + (lane >> 4) * 8 + j;
  wfrag[idx] = f2bf(W_enc[(cls * Ndim + n) * Kdim + k]);
}

// ---- kernel 2: front-end MLP: hgrid[bn][l][d] = fc4(relu(fc3(x))) , fp32 ----
__global__ __launch_bounds__(128) void frontend(
    const float* __restrict__ x, const float* __restrict__ fc3_w, const float* __restrict__ fc3_b,
    const float* __restrict__ fc4_w, const float* __restrict__ fc4_b, float* __restrict__ hgrid) {
  int row = blockIdx.x;  // bn*192 + l
  int t = threadIdx.x;   // 0..127
  __shared__ float xs[64];
  __shared__ float h1[128];
  if (t < 64) xs[t] = x[row * 64 + t];
  __syncthreads();
  float a = fc3_b[t];
#pragma unroll 8
  for (int c = 0; c < 64; ++c) a = fmaf(xs[c], fc3_w[t * 64 + c], a);
  h1[t] = fmaxf(a, 0.0f);
  __syncthreads();
  float b = fc4_b[t];
#pragma unroll 8
  for (int j2 = 0; j2 < 128; ++j2) b = fmaf(h1[j2], fc4_w[t * 128 + j2], b);
  hgrid[row * 128 + t] = b;
}

// ---- kernel 3: persistent per-(class,b) recurrence. 128 wgs x 256 threads ----
// A (16 x 384) rows = slices 0..11 (12..15 zero-pad):
//   k in [0,128)  : h_row[slice]
//   k in [128,256): h_col[(slice+11)%12]  (the rolled-in value, circular)
//   k in [256,384): x = hgrid[bn][(s-slice)*12 + slice] if 0<=s-slice<16 else 0
// g = A @ W.T  via mfma 16x16x32 bf16, activations split hi+lo bf16 (2 mfma/term).
__global__ __launch_bounds__(256) void witran(
    const float* __restrict__ hgrid, const short* __restrict__ wfrag,
    const float* __restrict__ B_enc,
    const float* __restrict__ fc1_w, const float* __restrict__ fc1_b,
    const float* __restrict__ fc2_w, const float* __restrict__ fc2_b,
    float* __restrict__ out) {
  int wg = blockIdx.x;
  int cls = wg & 1;
  int bn = wg >> 1;
  int t = threadIdx.x;
  int lane = t & 63;
  int wv = t >> 6;        // wave 0..3 -> output cols [wv*192, wv*192+192)
  int arow = lane & 15;   // MFMA A row = slice index
  int quad = lane >> 4;   // MFMA k-octet group

  __shared__ float hrow[12 * HSTR];
  __shared__ float hcol[2][12 * HSTR];  // ping-pong (roll semantics)
  __shared__ float bias[Ndim];
  __shared__ float g_lds[12 * GSTR];

  for (int i = t; i < 12 * HSTR; i += 256) {
    hrow[i] = 0.f;
    hcol[0][i] = 0.f;
    hcol[1][i] = 0.f;
  }
  for (int i = t; i < Ndim; i += 256) bias[i] = B_enc[cls * Ndim + i];
  __syncthreads();

  const float* hg = hgrid + (size_t)bn * 192 * Hdim;
  const short* wfc = wfrag + (size_t)cls * 48 * 12 * 512;

  for (int s = 0; s < Steps; ++s) {
    int cur = s & 1;

    // ---- build A fragments (hi/lo bf16) straight into registers ----
    short8 ahi[12], alo[12];
    {
      int k0q = quad * 8;
#pragma unroll
      for (int ks = 0; ks < 12; ++ks) {
        float v[8];
        if (arow < 12) {
          if (ks < 4) {
            const float* src = &hrow[arow * HSTR + ks * 32 + k0q];
#pragma unroll
            for (int i = 0; i < 8; ++i) v[i] = src[i];
          } else if (ks < 8) {
            const float* src = &hcol[cur][((arow + 11) % 12) * HSTR + (ks - 4) * 32 + k0q];
#pragma unroll
            for (int i = 0; i < 8; ++i) v[i] = src[i];
          } else {
            int r = s - arow;
            if (r >= 0 && r < 16) {
              const float* src = &hg[(r * 12 + arow) * Hdim + (ks - 8) * 32 + k0q];
#pragma unroll
              for (int i = 0; i < 8; ++i) v[i] = src[i];
            } else {
#pragma unroll
              for (int i = 0; i < 8; ++i) v[i] = 0.f;
            }
          }
        } else {
#pragma unroll
          for (int i = 0; i < 8; ++i) v[i] = 0.f;
        }
        short8 hi, lo;
#pragma unroll
        for (int i = 0; i < 8; ++i) {
          short h = f2bf(v[i]);
          hi[i] = h;
          lo[i] = f2bf(v[i] - bf2f(h));
        }
        ahi[ks] = hi;
        alo[ks] = lo;
      }
    }

    // ---- GEMM: stream B fragments from L2, accumulate, spill g to LDS ----
#pragma unroll
    for (int nt = 0; nt < 12; ++nt) {
      const short* bp = wfc + ((wv * 12 + nt) * 12) * 512 + lane * 8;
      f32x4 a = {0.f, 0.f, 0.f, 0.f};
#pragma unroll
      for (int ks = 0; ks < 12; ++ks) {
        short8 b = *(const short8*)(bp + ks * 512);
        a = __builtin_amdgcn_mfma_f32_16x16x32_bf16(ahi[ks], b, a, 0, 0, 0);
        a = __builtin_amdgcn_mfma_f32_16x16x32_bf16(alo[ks], b, a, 0, 0, 0);
      }
      if (quad < 3) {  // C/D rows = quad*4+r ; only rows 0..11 are real slices
        int col = wv * 192 + nt * 16 + arow;
#pragma unroll
        for (int r = 0; r < 4; ++r) g_lds[(quad * 4 + r) * GSTR + col] = a[r];
      }
    }
    __syncthreads();

    // ---- gated update (all 12 slices, matching reference semantics) ----
    bool sb = (s < 12);
#pragma unroll
    for (int ii = 0; ii < 6; ++ii) {
      int i = t + ii * 256;
      int c = i >> 7, d = i & 127;
      bool ab = sb && (c <= s);  // bias mask: (slice_id <= s) & (s < R)
      const float* gr = &g_lds[c * GSTR];
      float gur = gr[d] + (ab ? bias[d] : 0.f);
      float gor = gr[Hdim + d] + (ab ? bias[Hdim + d] : 0.f);
      float guc = gr[2 * Hdim + d] + (ab ? bias[2 * Hdim + d] : 0.f);
      float goc = gr[3 * Hdim + d] + (ab ? bias[3 * Hdim + d] : 0.f);
      float gir = gr[4 * Hdim + d] + (ab ? bias[4 * Hdim + d] : 0.f);
      float gic = gr[5 * Hdim + d] + (ab ? bias[5 * Hdim + d] : 0.f);
      float ur = sigmoidf_(gur), orr = sigmoidf_(gor);
      float uc = sigmoidf_(guc), oc = sigmoidf_(goc);
      float ir = tanh_(gir), ic = tanh_(gic);
      float hr_old = hrow[c * HSTR + d];
      float hc_old = hcol[cur][((c + 11) % 12) * HSTR + d];  // rolled-in value
      hrow[c * HSTR + d] = tanh_((1.f - ur) * hr_old + ur * ir) * orr;
      hcol[cur ^ 1][c * HSTR + d] = tanh_((1.f - uc) * hc_old + uc * ic) * oc;
    }
    __syncthreads();
  }

  // ---- epilogue: out = 0.5*(h_col[11]@fc1 + b1) + 0.5*(h_row[11]@fc2 + b2) ----
  if (t < 128) {
    float hc = hcol[Steps & 1][11 * HSTR + t];
    float hr = hrow[11 * HSTR + t];
    g_lds[t] = 0.5f * (hc * fc1_w[cls * 128 + t] + hr * fc2_w[cls * 128 + t]);
  }
  __syncthreads();
  if (t == 0) {
    float sum = 0.f;
    for (int i = 0; i < 128; ++i) sum += g_lds[i];
    sum += 0.5f * (fc1_b[cls] + fc2_b[cls]);
    out[bn * 2 + cls] = sum;
  }
}

extern "C" void kernel_launch(void* const* d_in, const int* in_sizes, int n_in,
                              void* d_out, int out_size, void* d_ws, size_t ws_size,
                              hipStream_t stream) {
  const float* x = (const float*)d_in[0];
  // d_in[1] = pad_mask: unused by the reference
  const float* fc3_w = (const float*)d_in[2];
  const float* fc3_b = (const float*)d_in[3];
  const float* fc4_w = (const float*)d_in[4];
  const float* fc4_b = (const float*)d_in[5];
  const float* W_enc = (const float*)d_in[6];
  const float* B_enc = (const float*)d_in[7];
  const float* fc1_w = (const float*)d_in[8];
  const float* fc1_b = (const float*)d_in[9];
  const float* fc2_w = (const float*)d_in[10];
  const float* fc2_b = (const float*)d_in[11];
  float* out = (float*)d_out;

  short* wfrag = (short*)d_ws;                      // 1,179,648 B
  float* hgrid = (float*)((char*)d_ws + 1179648);   // 6,291,456 B

  prep_w<<<dim3(2304), dim3(256), 0, stream>>>(W_enc, wfrag);
  frontend<<<dim3(12288), dim3(128), 0, stream>>>(x, fc3_w, fc3_b, fc4_w, fc4_b, hgrid);
  witran<<<dim3(128), dim3(256), 0, stream>>>(hgrid, wfrag, B_enc, fc1_w, fc1_b, fc2_w, fc2_b, out);
}

// Round 2
// 288.032 us; speedup vs baseline: 3.6795x; 3.6795x over previous
//
#include <hip/hip_runtime.h>

typedef short short8 __attribute__((ext_vector_type(8)));
typedef float f32x4 __attribute__((ext_vector_type(4)));

constexpr int Hdim = 128;   // H
constexpr int Steps = 27;   // COL + ROW - 1
constexpr int Kdim = 384;   // 3H
constexpr int Ndim = 768;   // 6H
constexpr int ASTR = 392;   // A-row stride in shorts (784 B = 49*16 -> 2-way LDS aliasing only)
constexpr int NGROUP = 128; // (cls, bn) pairs

__device__ __forceinline__ short f2bf(float f) {
  unsigned u = __float_as_uint(f);
  u += 0x7FFFu + ((u >> 16) & 1u);  // RNE
  return (short)(u >> 16);
}
__device__ __forceinline__ float bf2f(short s) {
  return __uint_as_float(((unsigned)(unsigned short)s) << 16);
}
__device__ __forceinline__ float sigmoidf_(float x) { return 1.0f / (1.0f + __expf(-x)); }
__device__ __forceinline__ float tanh_(float x) { return 1.0f - 2.0f / (__expf(2.0f * x) + 1.0f); }

#define ATOMIC_ST(p, v) __hip_atomic_store((p), (v), __ATOMIC_RELAXED, __HIP_MEMORY_SCOPE_AGENT)
#define ATOMIC_LD(p) __hip_atomic_load((p), __ATOMIC_RELAXED, __HIP_MEMORY_SCOPE_AGENT)

// ---- kernel 1: W_enc (fp32) -> MFMA B-fragment-ordered bf16 ----
// idx = ((cls*48 + nt)*12 + ks)*512 + lane*8 + j ; holds W[nt*16+(lane&15)][ks*32+(lane>>4)*8+j]
__global__ void prep_w(const float* __restrict__ W_enc, short* __restrict__ wfrag) {
  int idx = blockIdx.x * 256 + threadIdx.x;
  if (idx >= 2 * 48 * 12 * 512) return;
  int j = idx & 7;
  int lane = (idx >> 3) & 63;
  int rest = idx >> 9;
  int ks = rest % 12;
  int tmp = rest / 12;
  int nt = tmp % 48;
  int cls = tmp / 48;
  int n = nt * 16 + (lane & 15);
  int k = ks * 32 + (lane >> 4) * 8 + j;
  wfrag[idx] = f2bf(W_enc[(cls * Ndim + n) * Kdim + k]);
}

// ---- kernel 2: front-end MLP, 16 rows/block, fc weights register-cached ----
__global__ __launch_bounds__(128) void frontend16(
    const float* __restrict__ x, const float* __restrict__ fc3_w, const float* __restrict__ fc3_b,
    const float* __restrict__ fc4_w, const float* __restrict__ fc4_b,
    short* __restrict__ hg_hi, short* __restrict__ hg_lo) {
  const int t = threadIdx.x;
  const int row0 = blockIdx.x * 16;
  __shared__ float xs[64];
  __shared__ float h1[128];
  float w3[64], w4[128];
#pragma unroll
  for (int c = 0; c < 64; ++c) w3[c] = fc3_w[t * 64 + c];
#pragma unroll
  for (int c = 0; c < 128; ++c) w4[c] = fc4_w[t * 128 + c];
  const float b3 = fc3_b[t], b4 = fc4_b[t];
  for (int r = 0; r < 16; ++r) {
    const int row = row0 + r;
    if (t < 64) xs[t] = x[row * 64 + t];
    __syncthreads();
    float a = b3;
#pragma unroll
    for (int c = 0; c < 64; ++c) a = fmaf(xs[c], w3[c], a);
    h1[t] = fmaxf(a, 0.f);
    __syncthreads();
    float b = b4;
#pragma unroll
    for (int j = 0; j < 128; ++j) b = fmaf(h1[j], w4[j], b);
    short hb = f2bf(b);
    hg_hi[row * 128 + t] = hb;
    hg_lo[row * 128 + t] = f2bf(b - bf2f(hb));
    __syncthreads();
  }
}

// ---- kernel 3: 4-wg groups, register-resident weights, LLC gate exchange ----
__global__ __launch_bounds__(256, 2) void witran(
    const short* __restrict__ hg_hi, const short* __restrict__ hg_lo,
    const short* __restrict__ wfrag, const float* __restrict__ B_enc,
    const float* __restrict__ fc1_w, const float* __restrict__ fc1_b,
    const float* __restrict__ fc2_w, const float* __restrict__ fc2_b,
    float* __restrict__ g_buf, unsigned* __restrict__ flags, float* __restrict__ out) {
  const int wgq = blockIdx.x >> 7;    // 0..3 : N-stripe index (members = g + 128*q -> same XCD mod 8)
  const int group = blockIdx.x & 127; // (cls, bn)
  const int cls = group & 1;
  const int bn = group >> 1;
  const int t = threadIdx.x;
  const int lane = t & 63;
  const int wv = t >> 6;     // wave: cols [wgq*192 + wv*48, +48)
  const int arow = lane & 15;
  const int quad = lane >> 4;

  __shared__ __attribute__((aligned(16))) short Ahi[16 * ASTR];
  __shared__ __attribute__((aligned(16))) short Alo[16 * ASTR];
  __shared__ float bias[Ndim];
  __shared__ float red[128];

  for (int i = t; i < 16 * ASTR; i += 256) { Ahi[i] = 0; Alo[i] = 0; }
  for (int i = t; i < Ndim; i += 256) bias[i] = B_enc[cls * Ndim + i];

  // persistent weight fragments: wave wv owns nt = wgq*12 + wv*3 + {0,1,2}, all 12 ks
  short8 w0[12], w1[12], w2[12];
  {
    const short* wfc = wfrag + (size_t)cls * (48 * 12 * 512) + (size_t)lane * 8;
    const int ntb = wgq * 12 + wv * 3;
#pragma unroll
    for (int ks = 0; ks < 12; ++ks) w0[ks] = *(const short8*)(wfc + ((ntb + 0) * 12 + ks) * 512);
#pragma unroll
    for (int ks = 0; ks < 12; ++ks) w1[ks] = *(const short8*)(wfc + ((ntb + 1) * 12 + ks) * 512);
#pragma unroll
    for (int ks = 0; ks < 12; ++ks) w2[ks] = *(const short8*)(wfc + ((ntb + 2) * 12 + ks) * 512);
  }

  const short* hgh = hg_hi + (size_t)bn * 192 * Hdim;
  const short* hgl = hg_lo + (size_t)bn * 192 * Hdim;
  unsigned* flag = flags + group * 16;  // 64B padded

  __syncthreads();  // A zero-init complete before x fill

  // x segment for step 0 (A row c, k in [256,384))
  if (t < 192) {
    int c = t >> 4, j8 = (t & 15) * 8;
    short8 vh = {0, 0, 0, 0, 0, 0, 0, 0}, vl = vh;
    if (c == 0) {  // r = 0 - c valid only for c == 0
      vh = *(const short8*)(hgh + c * Hdim + j8);
      vl = *(const short8*)(hgl + c * Hdim + j8);
    }
    *(short8*)&Ahi[c * ASTR + 256 + j8] = vh;
    *(short8*)&Alo[c * ASTR + 256 + j8] = vl;
  }
  __syncthreads();

  const int abase = arow * ASTR + quad * 8;

  for (int s = 0; s < Steps; ++s) {
    // ---- GEMM: A (LDS, hi/lo bf16) x W (registers) ----
    f32x4 a0 = {0.f, 0.f, 0.f, 0.f}, a1 = a0, a2 = a0;
#pragma unroll
    for (int ks = 0; ks < 12; ++ks) {
      short8 ah = *(const short8*)&Ahi[abase + ks * 32];
      short8 al = *(const short8*)&Alo[abase + ks * 32];
      a0 = __builtin_amdgcn_mfma_f32_16x16x32_bf16(ah, w0[ks], a0, 0, 0, 0);
      a1 = __builtin_amdgcn_mfma_f32_16x16x32_bf16(ah, w1[ks], a1, 0, 0, 0);
      a2 = __builtin_amdgcn_mfma_f32_16x16x32_bf16(ah, w2[ks], a2, 0, 0, 0);
      a0 = __builtin_amdgcn_mfma_f32_16x16x32_bf16(al, w0[ks], a0, 0, 0, 0);
      a1 = __builtin_amdgcn_mfma_f32_16x16x32_bf16(al, w1[ks], a1, 0, 0, 0);
      a2 = __builtin_amdgcn_mfma_f32_16x16x32_bf16(al, w2[ks], a2, 0, 0, 0);
    }

    // ---- publish gate stripe (sc1 stores -> LLC, double-buffered by step parity) ----
    float* gb = g_buf + (size_t)(s & 1) * (NGROUP * 12 * Ndim) + (size_t)group * 12 * Ndim;
    if (quad < 3) {
      int colb = wgq * 192 + wv * 48 + arow;
#pragma unroll
      for (int r = 0; r < 4; ++r) {
        int row = quad * 4 + r;
        ATOMIC_ST(&gb[row * Ndim + colb + 0], a0[r]);
        ATOMIC_ST(&gb[row * Ndim + colb + 16], a1[r]);
        ATOMIC_ST(&gb[row * Ndim + colb + 32], a2[r]);
      }
    }
    __syncthreads();  // drains vmcnt: stripe globally visible before flag bump

    if (t == 0) {
      __hip_atomic_fetch_add(flag, 1u, __ATOMIC_RELAXED, __HIP_MEMORY_SCOPE_AGENT);
      const unsigned tgt = 4u * (s + 1);
      int guard = 0;
      while (ATOMIC_LD(flag) < tgt) {
        __builtin_amdgcn_s_sleep(1);
        if (++guard > (1 << 20)) break;  // deadlock valve (diagnostic, not correctness)
      }
    }
    __syncthreads();

    // ---- read old h states (LDS) before any thread overwrites ----
    float hro[6], hco[6];
#pragma unroll
    for (int ii = 0; ii < 6; ++ii) {
      int pos = t + ii * 256;
      int c = pos >> 7, d = pos & 127;
      hro[ii] = bf2f(Ahi[c * ASTR + d]) + bf2f(Alo[c * ASTR + d]);
      hco[ii] = bf2f(Ahi[c * ASTR + 128 + d]) + bf2f(Alo[c * ASTR + 128 + d]);
    }
    __syncthreads();

    // ---- gates (from LLC) + update; write h_row, rolled h_col into A ----
    const bool sb = (s < 12);
#pragma unroll
    for (int ii = 0; ii < 6; ++ii) {
      int pos = t + ii * 256;
      int c = pos >> 7, d = pos & 127;
      const float* gr = gb + c * Ndim;
      float g0 = ATOMIC_LD(&gr[d]);
      float g1 = ATOMIC_LD(&gr[Hdim + d]);
      float g2 = ATOMIC_LD(&gr[2 * Hdim + d]);
      float g3 = ATOMIC_LD(&gr[3 * Hdim + d]);
      float g4 = ATOMIC_LD(&gr[4 * Hdim + d]);
      float g5 = ATOMIC_LD(&gr[5 * Hdim + d]);
      if (sb && (c <= s)) {
        g0 += bias[d]; g1 += bias[Hdim + d]; g2 += bias[2 * Hdim + d];
        g3 += bias[3 * Hdim + d]; g4 += bias[4 * Hdim + d]; g5 += bias[5 * Hdim + d];
      }
      float ur = sigmoidf_(g0), orr = sigmoidf_(g1);
      float uc = sigmoidf_(g2), oc = sigmoidf_(g3);
      float ir = tanh_(g4), ic = tanh_(g5);
      float hr = tanh_((1.f - ur) * hro[ii] + ur * ir) * orr;
      float hc = tanh_((1.f - uc) * hco[ii] + uc * ic) * oc;
      short h1 = f2bf(hr);
      Ahi[c * ASTR + d] = h1;
      Alo[c * ASTR + d] = f2bf(hr - bf2f(h1));
      int c2 = (c == 11) ? 0 : c + 1;  // roll: new h_col[c] feeds slice c+1 next step
      short h2 = f2bf(hc);
      Ahi[c2 * ASTR + 128 + d] = h2;
      Alo[c2 * ASTR + 128 + d] = f2bf(hc - bf2f(h2));
    }

    // ---- x segment for step s+1 ----
    if (s < 26 && t < 192) {
      int c = t >> 4, j8 = (t & 15) * 8;
      int r = (s + 1) - c;
      short8 vh = {0, 0, 0, 0, 0, 0, 0, 0}, vl = vh;
      if (r >= 0 && r < 16) {
        vh = *(const short8*)(hgh + (r * 12 + c) * Hdim + j8);
        vl = *(const short8*)(hgl + (r * 12 + c) * Hdim + j8);
      }
      *(short8*)&Ahi[c * ASTR + 256 + j8] = vh;
      *(short8*)&Alo[c * ASTR + 256 + j8] = vl;
    }
    __syncthreads();
  }

  // ---- epilogue: h_row[11] at A[11][0:128), h_col_new[11] at A[0][128:256) ----
  if (t < 128) {
    float hr = bf2f(Ahi[11 * ASTR + t]) + bf2f(Alo[11 * ASTR + t]);
    float hc = bf2f(Ahi[0 * ASTR + 128 + t]) + bf2f(Alo[0 * ASTR + 128 + t]);
    red[t] = 0.5f * (hc * fc1_w[cls * Hdim + t] + hr * fc2_w[cls * Hdim + t]);
  }
  __syncthreads();
  if (wgq == 0 && t == 0) {
    float sum = 0.f;
    for (int i = 0; i < 128; ++i) sum += red[i];
    out[bn * 2 + cls] = sum + 0.5f * (fc1_b[cls] + fc2_b[cls]);
  }
}

extern "C" void kernel_launch(void* const* d_in, const int* in_sizes, int n_in,
                              void* d_out, int out_size, void* d_ws, size_t ws_size,
                              hipStream_t stream) {
  const float* x = (const float*)d_in[0];
  // d_in[1] = pad_mask: unused by the reference
  const float* fc3_w = (const float*)d_in[2];
  const float* fc3_b = (const float*)d_in[3];
  const float* fc4_w = (const float*)d_in[4];
  const float* fc4_b = (const float*)d_in[5];
  const float* W_enc = (const float*)d_in[6];
  const float* B_enc = (const float*)d_in[7];
  const float* fc1_w = (const float*)d_in[8];
  const float* fc1_b = (const float*)d_in[9];
  const float* fc2_w = (const float*)d_in[10];
  const float* fc2_b = (const float*)d_in[11];
  float* out = (float*)d_out;

  char* ws = (char*)d_ws;
  short* wfrag = (short*)ws;                       //  1,179,648 B
  short* hg_hi = (short*)(ws + 1179648);           //  3,145,728 B
  short* hg_lo = (short*)(ws + 4325376);           //  3,145,728 B
  float* g_buf = (float*)(ws + 7471104);           //  9,437,184 B (2x dbuf)
  unsigned* flags = (unsigned*)(ws + 16908288);    //      8,192 B
  // total 16,916,480 B

  hipMemsetAsync(flags, 0, 128 * 16 * sizeof(unsigned), stream);
  prep_w<<<dim3(2304), dim3(256), 0, stream>>>(W_enc, wfrag);
  frontend16<<<dim3(768), dim3(128), 0, stream>>>(x, fc3_w, fc3_b, fc4_w, fc4_b, hg_hi, hg_lo);
  witran<<<dim3(512), dim3(256), 0, stream>>>(hg_hi, hg_lo, wfrag, B_enc,
                                              fc1_w, fc1_b, fc2_w, fc2_b, g_buf, flags, out);
}